// Round 1
// baseline (4032.993 us; speedup 1.0000x reference)
//
#include <hip/hip_runtime.h>
#include <cstdint>
#include <cstddef>

// GPT-12-layer forward, bf16 MFMA pipeline.
// Layout conventions:
//   activations: rows = b*512 + l  (M = 8192), row-major, f32 master + bf16 copy
//   weights: pre-transposed per layer to Wt[N][K] bf16 (B^T GEMM input form)
// GEMM: 128x128 tile, BK=32, 4 waves (2x2), global_load_lds width-16 staging,
//       mfma_f32_16x16x32_bf16, fused bias (+gelu / +bf16-cast) epilogues.
// Attention: flash-style, block per (b, head, 64-q rows), K/V tiles in LDS
//       (XOR-swizzled), online softmax, P via padded per-wave LDS relayout.

#define LSEQ 512
#define NBATCH 16
#define EDIM 768
#define NHEAD 12
#define NLAYER 12

typedef __attribute__((ext_vector_type(8))) short short8;
typedef __attribute__((ext_vector_type(4))) float f32x4;

__device__ __forceinline__ short f2bf(float f) {
  union { float f; unsigned u; } x; x.f = f;
  return (short)((x.u + 0x7FFFu + ((x.u >> 16) & 1u)) >> 16);  // RNE
}

__device__ __forceinline__ void gload_lds16(const void* g, void* l) {
  __builtin_amdgcn_global_load_lds(
      (__attribute__((address_space(1))) void*)(void*)g,
      (__attribute__((address_space(3))) void*)l, 16, 0, 0);
}

// ---------------- weight transpose + bf16 convert: W[K][N] f32 -> Wt[N][K] bf16
__global__ __launch_bounds__(256) void wt_transpose(const float* __restrict__ W,
                                                    short* __restrict__ Wt,
                                                    int K, int N) {
  __shared__ float tile[32][33];
  const int n0 = blockIdx.x * 32, k0 = blockIdx.y * 32;
  const size_t lo = (size_t)blockIdx.z * K * N;
  const float* Ws = W + lo;
  short* Wd = Wt + lo;
  const int tx = threadIdx.x & 31, ty = threadIdx.x >> 5;  // 32 x 8
#pragma unroll
  for (int i = 0; i < 4; ++i)
    tile[ty + i * 8][tx] = Ws[(size_t)(k0 + ty + i * 8) * N + n0 + tx];
  __syncthreads();
#pragma unroll
  for (int i = 0; i < 4; ++i)
    Wd[(size_t)(n0 + ty + i * 8) * K + k0 + tx] = f2bf(tile[tx][ty + i * 8]);
}

// ---------------- embed: h[b*L+l][e] = x[l][b][e] + pos[l][e]
__global__ __launch_bounds__(256) void embed_k(const float* __restrict__ x,
                                               const float* __restrict__ pos,
                                               float* __restrict__ h,
                                               short* __restrict__ hbf) {
  const int row = blockIdx.x;  // b*512 + l
  const int b = row >> 9, lp = row & 511;
  const int t = threadIdx.x;
#pragma unroll
  for (int i = 0; i < 3; ++i) {
    const int e = t + i * 256;
    float v = x[(size_t)(lp * 16 + b) * 768 + e] + pos[(size_t)lp * 768 + e];
    h[(size_t)row * 768 + e] = v;
    hbf[(size_t)row * 768 + e] = f2bf(v);
  }
}

// ---------------- final: out[l][b][e] = h[b*L+l][e]
__global__ __launch_bounds__(256) void final_k(const float* __restrict__ h,
                                               float* __restrict__ out) {
  const int row = blockIdx.x;  // l*16 + b
  const int lp = row >> 4, b = row & 15;
  const int t = threadIdx.x;
#pragma unroll
  for (int i = 0; i < 3; ++i) {
    const int e = t + i * 256;
    out[(size_t)row * 768 + e] = h[(size_t)(b * 512 + lp) * 768 + e];
  }
}

// ---------------- fused residual-add + LayerNorm (writes f32 + bf16)
__global__ __launch_bounds__(256) void ln_fused(const float* __restrict__ A,
                                                const float* __restrict__ B,
                                                const float* __restrict__ g,
                                                const float* __restrict__ be,
                                                float* __restrict__ outf,
                                                short* __restrict__ outb) {
  const int row = blockIdx.x;
  const int t = threadIdx.x;
  const size_t base = (size_t)row * 768;
  float v[3];
  float s1 = 0.f, s2 = 0.f;
#pragma unroll
  for (int i = 0; i < 3; ++i) {
    const int e = t + i * 256;
    float xv = A[base + e] + B[base + e];
    v[i] = xv; s1 += xv; s2 += xv * xv;
  }
#pragma unroll
  for (int m = 1; m < 64; m <<= 1) {
    s1 += __shfl_xor(s1, m);
    s2 += __shfl_xor(s2, m);
  }
  __shared__ float r1[4], r2[4];
  const int w = t >> 6, l = t & 63;
  if (l == 0) { r1[w] = s1; r2[w] = s2; }
  __syncthreads();
  s1 = r1[0] + r1[1] + r1[2] + r1[3];
  s2 = r2[0] + r2[1] + r2[2] + r2[3];
  const float mu = s1 * (1.f / 768.f);
  const float var = s2 * (1.f / 768.f) - mu * mu;
  const float rs = rsqrtf(var + 1e-5f);
#pragma unroll
  for (int i = 0; i < 3; ++i) {
    const int e = t + i * 256;
    float o = (v[i] - mu) * rs * g[e] + be[e];
    outf[base + e] = o;
    outb[base + e] = f2bf(o);
  }
}

// ---------------- GEMM: C[M][N] = A[M][K] * Bt[N][K]^T + bias
// EPI: 0 = f32 out, 1 = bf16 out, 2 = gelu(bf16) out
template <int EPI>
__global__ __launch_bounds__(256) void gemm_bt(const short* __restrict__ A,
                                               const short* __restrict__ Bt,
                                               const float* __restrict__ bias,
                                               void* __restrict__ C,
                                               int N, int K) {
  __shared__ alignas(16) short Alds[128 * 32];
  __shared__ alignas(16) short Blds[128 * 32];
  const int t = threadIdx.x;
  const int w = t >> 6, l = t & 63;
  const int wr = w >> 1, wc = w & 1;
  const int l15 = l & 15, lhi = l >> 4;
  const int rowA0 = blockIdx.x * 128;
  const int rowB0 = blockIdx.y * 128;
  const f32x4 zero4 = {0.f, 0.f, 0.f, 0.f};
  f32x4 acc[4][4];
#pragma unroll
  for (int mi = 0; mi < 4; ++mi)
#pragma unroll
    for (int ni = 0; ni < 4; ++ni) acc[mi][ni] = zero4;

  const int lr = l >> 2;          // row within 16-row chunk (0..15)
  const int lcs = (l & 3) * 8;    // short offset within row (0/8/16/24)

  for (int kt = 0; kt < K; kt += 32) {
#pragma unroll
    for (int i = 0; i < 2; ++i) {
      const int r = i * 64 + w * 16 + lr;
      gload_lds16(A + (size_t)(rowA0 + r) * K + kt + lcs,
                  &Alds[(i * 64 + w * 16) * 32]);
      gload_lds16(Bt + (size_t)(rowB0 + r) * K + kt + lcs,
                  &Blds[(i * 64 + w * 16) * 32]);
    }
    __syncthreads();
    short8 af[4], bfr[4];
#pragma unroll
    for (int mi = 0; mi < 4; ++mi)
      af[mi] = *(const short8*)&Alds[(wr * 64 + mi * 16 + l15) * 32 + lhi * 8];
#pragma unroll
    for (int ni = 0; ni < 4; ++ni)
      bfr[ni] = *(const short8*)&Blds[(wc * 64 + ni * 16 + l15) * 32 + lhi * 8];
#pragma unroll
    for (int mi = 0; mi < 4; ++mi)
#pragma unroll
      for (int ni = 0; ni < 4; ++ni)
        acc[mi][ni] = __builtin_amdgcn_mfma_f32_16x16x32_bf16(
            af[mi], bfr[ni], acc[mi][ni], 0, 0, 0);
    __syncthreads();
  }

  float bv[4];
#pragma unroll
  for (int ni = 0; ni < 4; ++ni) bv[ni] = bias[rowB0 + wc * 64 + ni * 16 + l15];
#pragma unroll
  for (int mi = 0; mi < 4; ++mi) {
#pragma unroll
    for (int ni = 0; ni < 4; ++ni) {
      const int col = rowB0 + wc * 64 + ni * 16 + l15;
#pragma unroll
      for (int i = 0; i < 4; ++i) {
        const int row = rowA0 + wr * 64 + mi * 16 + lhi * 4 + i;
        float v = acc[mi][ni][i] + bv[ni];
        if constexpr (EPI == 0) {
          ((float*)C)[(size_t)row * N + col] = v;
        } else if constexpr (EPI == 1) {
          ((short*)C)[(size_t)row * N + col] = f2bf(v);
        } else {
          // HF gelu_new (tanh approx); tanh(z) = 1 - 2/(exp(2z)+1)
          float z = 0.7978845608028654f * (v + 0.044715f * v * v * v);
          float th = 1.0f - 2.0f / (__expf(2.0f * z) + 1.0f);
          ((short*)C)[(size_t)row * N + col] = f2bf(0.5f * v * (1.0f + th));
        }
      }
    }
  }
}

// ---------------- flash attention: block = (qb, head, batch), 4 waves
__global__ __launch_bounds__(256) void attn_k(const short* __restrict__ qkv,
                                              const float* __restrict__ mask,
                                              short* __restrict__ o) {
  const int qb = blockIdx.x;   // q block of 64 rows (0..7)
  const int hh = blockIdx.y;   // head
  const int b = blockIdx.z;    // batch
  const int t = threadIdx.x, w = t >> 6, l = t & 63;
  const int l15 = l & 15, lhi = l >> 4;
  __shared__ alignas(16) short Klds[64 * 64];
  __shared__ alignas(16) short Vlds[64 * 64];   // stored transposed: Vt[n][k]
  __shared__ alignas(16) short Plds[4][16 * 72];

  // Q fragments for this wave's 16 rows (A-operand: row=l&15, k=(l>>4)*8+j)
  short8 qa[2];
  {
    const size_t base =
        (size_t)(b * LSEQ + qb * 64 + w * 16 + l15) * 2304 + hh * 64;
    qa[0] = *(const short8*)&qkv[base + lhi * 8];
    qa[1] = *(const short8*)&qkv[base + 32 + lhi * 8];
  }
  float mrow[4] = {-1e30f, -1e30f, -1e30f, -1e30f};
  float lrow[4] = {0.f, 0.f, 0.f, 0.f};
  const f32x4 zero4 = {0.f, 0.f, 0.f, 0.f};
  f32x4 oacc[4];
#pragma unroll
  for (int nt = 0; nt < 4; ++nt) oacc[nt] = zero4;

  const int nkt = qb + 1;  // causal: only tiles up to the diagonal
  for (int kt = 0; kt < nkt; ++kt) {
    __syncthreads();  // previous iteration's K/V/P reads complete
    {
      const int kr = t >> 2, cc = (t & 3) * 16;
      const size_t grow = (size_t)(b * LSEQ + kt * 64 + kr) * 2304 + hh * 64;
      short8 k0 = *(const short8*)&qkv[grow + 768 + cc];
      short8 k1 = *(const short8*)&qkv[grow + 768 + cc + 8];
      short8 v0 = *(const short8*)&qkv[grow + 1536 + cc];
      short8 v1 = *(const short8*)&qkv[grow + 1536 + cc + 8];
      const int sw = (kr & 7) << 4;
      *(short8*)((char*)Klds + ((kr * 128 + cc * 2) ^ sw)) = k0;
      *(short8*)((char*)Klds + ((kr * 128 + cc * 2 + 16) ^ sw)) = k1;
#pragma unroll
      for (int e = 0; e < 8; ++e) {
        const int n0 = cc + e, n1 = cc + 8 + e;
        ((short*)Vlds)[((n0 * 128 + kr * 2) ^ ((n0 & 7) << 4)) >> 1] = v0[e];
        ((short*)Vlds)[((n1 * 128 + kr * 2) ^ ((n1 & 7) << 4)) >> 1] = v1[e];
      }
    }
    __syncthreads();

    // S = Q K^T  (B-operand: K row jt*16+(l&15), contiguous k)
    f32x4 s[4];
#pragma unroll
    for (int jt = 0; jt < 4; ++jt) {
      f32x4 z = zero4;
#pragma unroll
      for (int kc = 0; kc < 2; ++kc) {
        const int rowk = jt * 16 + l15;
        short8 kb = *(const short8*)((char*)Klds +
                     ((rowk * 128 + kc * 64 + lhi * 16) ^ ((rowk & 7) << 4)));
        z = __builtin_amdgcn_mfma_f32_16x16x32_bf16(qa[kc], kb, z, 0, 0, 0);
      }
      s[jt] = z;
    }

    // scale, causal mask (-10000), padding add_mask
    float addm[4];
#pragma unroll
    for (int jt = 0; jt < 4; ++jt)
      addm[jt] = (1.0f - mask[b * LSEQ + kt * 64 + jt * 16 + l15]) *
                 -3.402823466e38f;
#pragma unroll
    for (int jt = 0; jt < 4; ++jt) {
      const int colg = kt * 64 + jt * 16 + l15;
#pragma unroll
      for (int i = 0; i < 4; ++i) {
        const int rowg = qb * 64 + w * 16 + lhi * 4 + i;
        float sv = s[jt][i] * 0.125f;
        if (colg > rowg) sv = -10000.0f;
        s[jt][i] = sv + addm[jt];
      }
    }

    // online softmax (row spread over 16 lanes; rows = (l>>4)*4+i)
    float mnew[4], sc[4];
#pragma unroll
    for (int i = 0; i < 4; ++i) {
      float tm = fmaxf(fmaxf(s[0][i], s[1][i]), fmaxf(s[2][i], s[3][i]));
#pragma unroll
      for (int mm = 1; mm < 16; mm <<= 1) tm = fmaxf(tm, __shfl_xor(tm, mm));
      mnew[i] = fmaxf(mrow[i], tm);
      sc[i] = __expf(mrow[i] - mnew[i]);
      mrow[i] = mnew[i];
    }
#pragma unroll
    for (int i = 0; i < 4; ++i) {
      float ts = 0.f;
#pragma unroll
      for (int jt = 0; jt < 4; ++jt) {
        float p = __expf(s[jt][i] - mnew[i]);
        s[jt][i] = p;
        ts += p;
      }
#pragma unroll
      for (int mm = 1; mm < 16; mm <<= 1) ts += __shfl_xor(ts, mm);
      lrow[i] = lrow[i] * sc[i] + ts;
      oacc[0][i] *= sc[i]; oacc[1][i] *= sc[i];
      oacc[2][i] *= sc[i]; oacc[3][i] *= sc[i];
    }

    // P relayout via per-wave LDS (pitch 72 shorts = 144B, 16B-aligned rows)
    short* Pw = &Plds[w][0];
#pragma unroll
    for (int jt = 0; jt < 4; ++jt)
#pragma unroll
      for (int i = 0; i < 4; ++i)
        Pw[(lhi * 4 + i) * 72 + jt * 16 + l15] = f2bf(s[jt][i]);
    __syncthreads();
    short8 pa[2];
#pragma unroll
    for (int kc = 0; kc < 2; ++kc)
      pa[kc] = *(const short8*)&Pw[l15 * 72 + kc * 32 + lhi * 8];

    // O += P V   (B-operand from transposed Vt[n][k])
#pragma unroll
    for (int nt = 0; nt < 4; ++nt) {
#pragma unroll
      for (int kc = 0; kc < 2; ++kc) {
        const int rown = nt * 16 + l15;
        short8 vb = *(const short8*)((char*)Vlds +
                     ((rown * 128 + kc * 64 + lhi * 16) ^ ((rown & 7) << 4)));
        oacc[nt] = __builtin_amdgcn_mfma_f32_16x16x32_bf16(pa[kc], vb,
                                                           oacc[nt], 0, 0, 0);
      }
    }
  }

#pragma unroll
  for (int i = 0; i < 4; ++i) {
    const size_t row = (size_t)(b * LSEQ + qb * 64 + w * 16 + lhi * 4 + i);
    const float inv = 1.0f / lrow[i];
#pragma unroll
    for (int nt = 0; nt < 4; ++nt)
      o[row * 768 + hh * 64 + nt * 16 + l15] = f2bf(oacc[nt][i] * inv);
  }
}

// =====================================================================
extern "C" void kernel_launch(void* const* d_in, const int* in_sizes, int n_in,
                              void* d_out, int out_size, void* d_ws,
                              size_t ws_size, hipStream_t stream) {
  const float* x    = (const float*)d_in[0];
  const float* mask = (const float*)d_in[1];
  const float* pos  = (const float*)d_in[2];
  const float* caw  = (const float*)d_in[3];
  const float* cab  = (const float*)d_in[4];
  const float* apw  = (const float*)d_in[5];
  const float* apb  = (const float*)d_in[6];
  const float* g1   = (const float*)d_in[7];
  const float* b1   = (const float*)d_in[8];
  const float* fw   = (const float*)d_in[9];
  const float* fb   = (const float*)d_in[10];
  const float* pw   = (const float*)d_in[11];
  const float* pb   = (const float*)d_in[12];
  const float* g2   = (const float*)d_in[13];
  const float* b2   = (const float*)d_in[14];

  char* ws = (char*)d_ws;
  size_t off = 0;
  auto alloc = [&](size_t bytes) {
    size_t o = off;
    off += (bytes + 255) & ~(size_t)255;
    return o;
  };
  float* h    = (float*)(ws + alloc(8192ull * 768 * 4));
  short* hbf  = (short*)(ws + alloc(8192ull * 768 * 2));
  float* nrm  = (float*)(ws + alloc(8192ull * 768 * 4));
  short* nbf  = (short*)(ws + alloc(8192ull * 768 * 2));
  short* qkvb = (short*)(ws + alloc(8192ull * 2304 * 2));
  short* obf  = (short*)(ws + alloc(8192ull * 768 * 2));
  float* aout = (float*)(ws + alloc(8192ull * 768 * 4));  // also mlp out (aliased)
  short* gbf  = (short*)(ws + alloc(8192ull * 3072 * 2));
  short* wt_attn = (short*)(ws + alloc(12ull * 768 * 2304 * 2));
  short* wt_proj = (short*)(ws + alloc(12ull * 768 * 768 * 2));
  short* wt_fc   = (short*)(ws + alloc(12ull * 768 * 3072 * 2));
  short* wt_mlp  = (short*)(ws + alloc(12ull * 3072 * 768 * 2));
  (void)ws_size; (void)in_sizes; (void)n_in; (void)out_size;

  // weight bf16 transposes (per replay; ~510MB traffic, amortized small)
  wt_transpose<<<dim3(2304 / 32, 768 / 32, 12), 256, 0, stream>>>(caw, wt_attn, 768, 2304);
  wt_transpose<<<dim3(768 / 32, 768 / 32, 12), 256, 0, stream>>>(apw, wt_proj, 768, 768);
  wt_transpose<<<dim3(3072 / 32, 768 / 32, 12), 256, 0, stream>>>(fw, wt_fc, 768, 3072);
  wt_transpose<<<dim3(768 / 32, 3072 / 32, 12), 256, 0, stream>>>(pw, wt_mlp, 3072, 768);

  embed_k<<<8192, 256, 0, stream>>>(x, pos, h, hbf);

  for (int L = 0; L < 12; ++L) {
    gemm_bt<1><<<dim3(64, 18), 256, 0, stream>>>(
        hbf, wt_attn + (size_t)L * 2304 * 768, cab + (size_t)L * 2304, qkvb, 2304, 768);
    attn_k<<<dim3(8, 12, 16), 256, 0, stream>>>(qkvb, mask, obf);
    gemm_bt<0><<<dim3(64, 6), 256, 0, stream>>>(
        obf, wt_proj + (size_t)L * 768 * 768, apb + (size_t)L * 768, aout, 768, 768);
    ln_fused<<<8192, 256, 0, stream>>>(h, aout, g1 + (size_t)L * 768,
                                       b1 + (size_t)L * 768, nrm, nbf);
    gemm_bt<2><<<dim3(64, 24), 256, 0, stream>>>(
        nbf, wt_fc + (size_t)L * 768 * 3072, fb + (size_t)L * 3072, gbf, 3072, 768);
    gemm_bt<0><<<dim3(64, 6), 256, 0, stream>>>(
        gbf, wt_mlp + (size_t)L * 3072 * 768, pb + (size_t)L * 768, aout, 768, 3072);
    ln_fused<<<8192, 256, 0, stream>>>(nrm, aout, g2 + (size_t)L * 768,
                                       b2 + (size_t)L * 768, h, hbf);
  }

  final_k<<<8192, 256, 0, stream>>>(h, (float*)d_out);
}

// Round 2
// 3372.095 us; speedup vs baseline: 1.1960x; 1.1960x over previous
//
#include <hip/hip_runtime.h>
#include <cstdint>
#include <cstddef>

// GPT-12-layer forward, bf16 MFMA pipeline.
//   activations: rows = b*512 + l  (M = 8192), row-major, f32 master + bf16 copy
//   weights: pre-transposed per layer to Wt[N][K] bf16 (B^T GEMM input form)
// GEMM: 128xTN tile (TN=128 or 64), BK=64, 4 waves, global_load_lds width-16
//       staging with pre-swizzled source (T2: slot ^= row&7 on 16B slots),
//       mfma_f32_16x16x32_bf16, fused bias (+gelu / +bf16-cast) epilogues.
// Attention: flash-style, block per (b, head, 64-q rows), K/V tiles in LDS
//       (XOR-swizzled), online softmax, P via padded per-wave LDS relayout.

#define LSEQ 512
#define NBATCH 16
#define EDIM 768
#define NHEAD 12
#define NLAYER 12

typedef __attribute__((ext_vector_type(8))) short short8;
typedef __attribute__((ext_vector_type(4))) float f32x4;

__device__ __forceinline__ short f2bf(float f) {
  union { float f; unsigned u; } x; x.f = f;
  return (short)((x.u + 0x7FFFu + ((x.u >> 16) & 1u)) >> 16);  // RNE
}

__device__ __forceinline__ void gload_lds16(const void* g, void* l) {
  __builtin_amdgcn_global_load_lds(
      (__attribute__((address_space(1))) void*)(void*)g,
      (__attribute__((address_space(3))) void*)l, 16, 0, 0);
}

// ---------------- weight transpose + bf16 convert: W[K][N] f32 -> Wt[N][K] bf16
__global__ __launch_bounds__(256) void wt_transpose(const float* __restrict__ W,
                                                    short* __restrict__ Wt,
                                                    int K, int N) {
  __shared__ float tile[32][33];
  const int n0 = blockIdx.x * 32, k0 = blockIdx.y * 32;
  const size_t lo = (size_t)blockIdx.z * K * N;
  const float* Ws = W + lo;
  short* Wd = Wt + lo;
  const int tx = threadIdx.x & 31, ty = threadIdx.x >> 5;  // 32 x 8
#pragma unroll
  for (int i = 0; i < 4; ++i)
    tile[ty + i * 8][tx] = Ws[(size_t)(k0 + ty + i * 8) * N + n0 + tx];
  __syncthreads();
#pragma unroll
  for (int i = 0; i < 4; ++i)
    Wd[(size_t)(n0 + ty + i * 8) * K + k0 + tx] = f2bf(tile[tx][ty + i * 8]);
}

// ---------------- embed: h[b*L+l][e] = x[l][b][e] + pos[l][e]
__global__ __launch_bounds__(256) void embed_k(const float* __restrict__ x,
                                               const float* __restrict__ pos,
                                               float* __restrict__ h,
                                               short* __restrict__ hbf) {
  const int row = blockIdx.x;  // b*512 + l
  const int b = row >> 9, lp = row & 511;
  const int t = threadIdx.x;
#pragma unroll
  for (int i = 0; i < 3; ++i) {
    const int e = t + i * 256;
    float v = x[(size_t)(lp * 16 + b) * 768 + e] + pos[(size_t)lp * 768 + e];
    h[(size_t)row * 768 + e] = v;
    hbf[(size_t)row * 768 + e] = f2bf(v);
  }
}

// ---------------- final: out[l][b][e] = h[b*L+l][e]
__global__ __launch_bounds__(256) void final_k(const float* __restrict__ h,
                                               float* __restrict__ out) {
  const int row = blockIdx.x;  // l*16 + b
  const int lp = row >> 4, b = row & 15;
  const int t = threadIdx.x;
#pragma unroll
  for (int i = 0; i < 3; ++i) {
    const int e = t + i * 256;
    out[(size_t)row * 768 + e] = h[(size_t)(b * 512 + lp) * 768 + e];
  }
}

// ---------------- fused residual-add + LayerNorm (writes f32 + bf16)
__global__ __launch_bounds__(256) void ln_fused(const float* __restrict__ A,
                                                const float* __restrict__ B,
                                                const float* __restrict__ g,
                                                const float* __restrict__ be,
                                                float* __restrict__ outf,
                                                short* __restrict__ outb) {
  const int row = blockIdx.x;
  const int t = threadIdx.x;
  const size_t base = (size_t)row * 768;
  float v[3];
  float s1 = 0.f, s2 = 0.f;
#pragma unroll
  for (int i = 0; i < 3; ++i) {
    const int e = t + i * 256;
    float xv = A[base + e] + B[base + e];
    v[i] = xv; s1 += xv; s2 += xv * xv;
  }
#pragma unroll
  for (int m = 1; m < 64; m <<= 1) {
    s1 += __shfl_xor(s1, m);
    s2 += __shfl_xor(s2, m);
  }
  __shared__ float r1[4], r2[4];
  const int w = t >> 6, l = t & 63;
  if (l == 0) { r1[w] = s1; r2[w] = s2; }
  __syncthreads();
  s1 = r1[0] + r1[1] + r1[2] + r1[3];
  s2 = r2[0] + r2[1] + r2[2] + r2[3];
  const float mu = s1 * (1.f / 768.f);
  const float var = s2 * (1.f / 768.f) - mu * mu;
  const float rs = rsqrtf(var + 1e-5f);
#pragma unroll
  for (int i = 0; i < 3; ++i) {
    const int e = t + i * 256;
    float o = (v[i] - mu) * rs * g[e] + be[e];
    outf[base + e] = o;
    outb[base + e] = f2bf(o);
  }
}

// ---------------- GEMM: C[M][N] = A[M][K] * Bt[N][K]^T + bias
// Tile 128 x TN, BK=64, XOR-swizzled LDS (16B slot ^= row&7), 4 waves.
// EPI: 0 = f32 out, 1 = bf16 out, 2 = gelu(bf16) out
template <int TN, int EPI>
__global__ __launch_bounds__(256) void gemm_bt(const short* __restrict__ A,
                                               const short* __restrict__ Bt,
                                               const float* __restrict__ bias,
                                               void* __restrict__ C,
                                               int N, int K) {
  constexpr int BK = 64;  // shorts per row; row = 128B = 8 x 16B slots
  __shared__ alignas(16) short Alds[128 * BK];
  __shared__ alignas(16) short Blds[TN * BK];
  const int t = threadIdx.x;
  const int w = t >> 6, l = t & 63;
  constexpr int WR = (TN == 128) ? 2 : 4;   // wave grid rows
  constexpr int WC = (TN == 128) ? 2 : 1;   // wave grid cols
  constexpr int WM = 128 / WR;              // rows per wave (64 or 32)
  constexpr int MI = WM / 16;               // 4 or 2
  constexpr int NI = (TN / WC) / 16;        // 4
  const int wr = (WC == 2) ? (w >> 1) : w;
  const int wc = (WC == 2) ? (w & 1) : 0;
  const int l15 = l & 15, lhi = l >> 4;
  const int rowA0 = blockIdx.x * 128;
  const int rowB0 = blockIdx.y * TN;
  f32x4 acc[MI][NI];
#pragma unroll
  for (int mi = 0; mi < MI; ++mi)
#pragma unroll
    for (int ni = 0; ni < NI; ++ni) acc[mi][ni] = (f32x4){0.f, 0.f, 0.f, 0.f};

  // staging geometry: thread t covers LDS bytes chunk*4096 + t*16
  //   -> row r = chunk*32 + w*8 + (l>>3), slot s = l&7 (16B slots)
  // LDS slot s holds global k-slot s^(r&7)  (pre-swizzled source)
  const int srl = l >> 3;        // row within 8-row wave chunk
  const int ss = l & 7;          // slot index

  for (int kt = 0; kt < K; kt += BK) {
#pragma unroll
    for (int i = 0; i < 4; ++i) {  // A: 128 rows = 4 chunks of 32
      const int r = i * 32 + w * 8 + srl;
      gload_lds16(A + (size_t)(rowA0 + r) * K + kt + ((ss ^ (r & 7)) << 3),
                  &Alds[i * 2048 + w * 512]);
    }
#pragma unroll
    for (int i = 0; i < TN / 32; ++i) {  // B: TN rows
      const int r = i * 32 + w * 8 + srl;
      gload_lds16(Bt + (size_t)(rowB0 + r) * K + kt + ((ss ^ (r & 7)) << 3),
                  &Blds[i * 2048 + w * 512]);
    }
    __syncthreads();
    short8 af[MI][2], bfr[NI][2];
#pragma unroll
    for (int mi = 0; mi < MI; ++mi) {
      const int r = wr * WM + mi * 16 + l15;
#pragma unroll
      for (int kc = 0; kc < 2; ++kc)
        af[mi][kc] = *(const short8*)
            &Alds[r * 64 + ((((kc << 2) | lhi) ^ (r & 7)) << 3)];
    }
#pragma unroll
    for (int ni = 0; ni < NI; ++ni) {
      const int r = wc * 64 + ni * 16 + l15;
#pragma unroll
      for (int kc = 0; kc < 2; ++kc)
        bfr[ni][kc] = *(const short8*)
            &Blds[r * 64 + ((((kc << 2) | lhi) ^ (r & 7)) << 3)];
    }
#pragma unroll
    for (int mi = 0; mi < MI; ++mi)
#pragma unroll
      for (int ni = 0; ni < NI; ++ni)
#pragma unroll
        for (int kc = 0; kc < 2; ++kc)
          acc[mi][ni] = __builtin_amdgcn_mfma_f32_16x16x32_bf16(
              af[mi][kc], bfr[ni][kc], acc[mi][ni], 0, 0, 0);
    __syncthreads();
  }

  float bv[NI];
#pragma unroll
  for (int ni = 0; ni < NI; ++ni) bv[ni] = bias[rowB0 + wc * 64 + ni * 16 + l15];
#pragma unroll
  for (int mi = 0; mi < MI; ++mi) {
#pragma unroll
    for (int ni = 0; ni < NI; ++ni) {
      const int col = rowB0 + wc * 64 + ni * 16 + l15;
#pragma unroll
      for (int i = 0; i < 4; ++i) {
        const int row = rowA0 + wr * WM + mi * 16 + lhi * 4 + i;
        float v = acc[mi][ni][i] + bv[ni];
        if constexpr (EPI == 0) {
          ((float*)C)[(size_t)row * N + col] = v;
        } else if constexpr (EPI == 1) {
          ((short*)C)[(size_t)row * N + col] = f2bf(v);
        } else {
          // HF gelu_new (tanh approx); tanh(z) = 1 - 2/(exp(2z)+1)
          float z = 0.7978845608028654f * (v + 0.044715f * v * v * v);
          float th = 1.0f - 2.0f / (__expf(2.0f * z) + 1.0f);
          ((short*)C)[(size_t)row * N + col] = f2bf(0.5f * v * (1.0f + th));
        }
      }
    }
  }
}

// ---------------- flash attention: block = (qb, head, batch), 4 waves
__global__ __launch_bounds__(256) void attn_k(const short* __restrict__ qkv,
                                              const float* __restrict__ mask,
                                              short* __restrict__ o) {
  const int qb = blockIdx.x;   // q block of 64 rows (0..7)
  const int hh = blockIdx.y;   // head
  const int b = blockIdx.z;    // batch
  const int t = threadIdx.x, w = t >> 6, l = t & 63;
  const int l15 = l & 15, lhi = l >> 4;
  __shared__ alignas(16) short Klds[64 * 64];
  __shared__ alignas(16) short Vlds[64 * 64];   // stored transposed: Vt[n][k]
  __shared__ alignas(16) short Plds[4][16 * 72];

  // Q fragments for this wave's 16 rows (A-operand: row=l&15, k=(l>>4)*8+j)
  short8 qa[2];
  {
    const size_t base =
        (size_t)(b * LSEQ + qb * 64 + w * 16 + l15) * 2304 + hh * 64;
    qa[0] = *(const short8*)&qkv[base + lhi * 8];
    qa[1] = *(const short8*)&qkv[base + 32 + lhi * 8];
  }
  float mrow[4] = {-1e30f, -1e30f, -1e30f, -1e30f};
  float lrow[4] = {0.f, 0.f, 0.f, 0.f};
  const f32x4 zero4 = {0.f, 0.f, 0.f, 0.f};
  f32x4 oacc[4];
#pragma unroll
  for (int nt = 0; nt < 4; ++nt) oacc[nt] = zero4;

  const int nkt = qb + 1;  // causal: only tiles up to the diagonal
  for (int kt = 0; kt < nkt; ++kt) {
    __syncthreads();  // previous iteration's K/V/P reads complete
    {
      const int kr = t >> 2, cc = (t & 3) * 16;
      const size_t grow = (size_t)(b * LSEQ + kt * 64 + kr) * 2304 + hh * 64;
      short8 k0 = *(const short8*)&qkv[grow + 768 + cc];
      short8 k1 = *(const short8*)&qkv[grow + 768 + cc + 8];
      short8 v0 = *(const short8*)&qkv[grow + 1536 + cc];
      short8 v1 = *(const short8*)&qkv[grow + 1536 + cc + 8];
      const int sw = (kr & 7) << 4;
      *(short8*)((char*)Klds + ((kr * 128 + cc * 2) ^ sw)) = k0;
      *(short8*)((char*)Klds + ((kr * 128 + cc * 2 + 16) ^ sw)) = k1;
#pragma unroll
      for (int e = 0; e < 8; ++e) {
        const int n0 = cc + e, n1 = cc + 8 + e;
        ((short*)Vlds)[((n0 * 128 + kr * 2) ^ ((n0 & 7) << 4)) >> 1] = v0[e];
        ((short*)Vlds)[((n1 * 128 + kr * 2) ^ ((n1 & 7) << 4)) >> 1] = v1[e];
      }
    }
    __syncthreads();

    // S = Q K^T  (B-operand: K row jt*16+(l&15), contiguous k)
    f32x4 s[4];
#pragma unroll
    for (int jt = 0; jt < 4; ++jt) {
      f32x4 z = zero4;
#pragma unroll
      for (int kc = 0; kc < 2; ++kc) {
        const int rowk = jt * 16 + l15;
        short8 kb = *(const short8*)((char*)Klds +
                     ((rowk * 128 + kc * 64 + lhi * 16) ^ ((rowk & 7) << 4)));
        z = __builtin_amdgcn_mfma_f32_16x16x32_bf16(qa[kc], kb, z, 0, 0, 0);
      }
      s[jt] = z;
    }

    // scale, causal mask (-10000), padding add_mask
    float addm[4];
#pragma unroll
    for (int jt = 0; jt < 4; ++jt)
      addm[jt] = (1.0f - mask[b * LSEQ + kt * 64 + jt * 16 + l15]) *
                 -3.402823466e38f;
#pragma unroll
    for (int jt = 0; jt < 4; ++jt) {
      const int colg = kt * 64 + jt * 16 + l15;
#pragma unroll
      for (int i = 0; i < 4; ++i) {
        const int rowg = qb * 64 + w * 16 + lhi * 4 + i;
        float sv = s[jt][i] * 0.125f;
        if (colg > rowg) sv = -10000.0f;
        s[jt][i] = sv + addm[jt];
      }
    }

    // online softmax (row spread over 16 lanes; rows = (l>>4)*4+i)
    float mnew[4], sc[4];
#pragma unroll
    for (int i = 0; i < 4; ++i) {
      float tm = fmaxf(fmaxf(s[0][i], s[1][i]), fmaxf(s[2][i], s[3][i]));
#pragma unroll
      for (int mm = 1; mm < 16; mm <<= 1) tm = fmaxf(tm, __shfl_xor(tm, mm));
      mnew[i] = fmaxf(mrow[i], tm);
      sc[i] = __expf(mrow[i] - mnew[i]);
      mrow[i] = mnew[i];
    }
#pragma unroll
    for (int i = 0; i < 4; ++i) {
      float ts = 0.f;
#pragma unroll
      for (int jt = 0; jt < 4; ++jt) {
        float p = __expf(s[jt][i] - mnew[i]);
        s[jt][i] = p;
        ts += p;
      }
#pragma unroll
      for (int mm = 1; mm < 16; mm <<= 1) ts += __shfl_xor(ts, mm);
      lrow[i] = lrow[i] * sc[i] + ts;
      oacc[0][i] *= sc[i]; oacc[1][i] *= sc[i];
      oacc[2][i] *= sc[i]; oacc[3][i] *= sc[i];
    }

    // P relayout via per-wave LDS (pitch 72 shorts = 144B, 16B-aligned rows)
    short* Pw = &Plds[w][0];
#pragma unroll
    for (int jt = 0; jt < 4; ++jt)
#pragma unroll
      for (int i = 0; i < 4; ++i)
        Pw[(lhi * 4 + i) * 72 + jt * 16 + l15] = f2bf(s[jt][i]);
    __syncthreads();
    short8 pa[2];
#pragma unroll
    for (int kc = 0; kc < 2; ++kc)
      pa[kc] = *(const short8*)&Pw[l15 * 72 + kc * 32 + lhi * 8];

    // O += P V   (B-operand from transposed Vt[n][k])
#pragma unroll
    for (int nt = 0; nt < 4; ++nt) {
#pragma unroll
      for (int kc = 0; kc < 2; ++kc) {
        const int rown = nt * 16 + l15;
        short8 vb = *(const short8*)((char*)Vlds +
                     ((rown * 128 + kc * 64 + lhi * 16) ^ ((rown & 7) << 4)));
        oacc[nt] = __builtin_amdgcn_mfma_f32_16x16x32_bf16(pa[kc], vb,
                                                           oacc[nt], 0, 0, 0);
      }
    }
  }

#pragma unroll
  for (int i = 0; i < 4; ++i) {
    const size_t row = (size_t)(b * LSEQ + qb * 64 + w * 16 + lhi * 4 + i);
    const float inv = 1.0f / lrow[i];
#pragma unroll
    for (int nt = 0; nt < 4; ++nt)
      o[row * 768 + hh * 64 + nt * 16 + l15] = f2bf(oacc[nt][i] * inv);
  }
}

// =====================================================================
extern "C" void kernel_launch(void* const* d_in, const int* in_sizes, int n_in,
                              void* d_out, int out_size, void* d_ws,
                              size_t ws_size, hipStream_t stream) {
  const float* x    = (const float*)d_in[0];
  const float* mask = (const float*)d_in[1];
  const float* pos  = (const float*)d_in[2];
  const float* caw  = (const float*)d_in[3];
  const float* cab  = (const float*)d_in[4];
  const float* apw  = (const float*)d_in[5];
  const float* apb  = (const float*)d_in[6];
  const float* g1   = (const float*)d_in[7];
  const float* b1   = (const float*)d_in[8];
  const float* fw   = (const float*)d_in[9];
  const float* fb   = (const float*)d_in[10];
  const float* pw   = (const float*)d_in[11];
  const float* pb   = (const float*)d_in[12];
  const float* g2   = (const float*)d_in[13];
  const float* b2   = (const float*)d_in[14];

  char* ws = (char*)d_ws;
  size_t off = 0;
  auto alloc = [&](size_t bytes) {
    size_t o = off;
    off += (bytes + 255) & ~(size_t)255;
    return o;
  };
  float* h    = (float*)(ws + alloc(8192ull * 768 * 4));
  short* hbf  = (short*)(ws + alloc(8192ull * 768 * 2));
  float* nrm  = (float*)(ws + alloc(8192ull * 768 * 4));
  short* nbf  = (short*)(ws + alloc(8192ull * 768 * 2));
  short* qkvb = (short*)(ws + alloc(8192ull * 2304 * 2));
  short* obf  = (short*)(ws + alloc(8192ull * 768 * 2));
  float* aout = (float*)(ws + alloc(8192ull * 768 * 4));  // also mlp out (aliased)
  short* gbf  = (short*)(ws + alloc(8192ull * 3072 * 2));
  short* wt_attn = (short*)(ws + alloc(12ull * 768 * 2304 * 2));
  short* wt_proj = (short*)(ws + alloc(12ull * 768 * 768 * 2));
  short* wt_fc   = (short*)(ws + alloc(12ull * 768 * 3072 * 2));
  short* wt_mlp  = (short*)(ws + alloc(12ull * 3072 * 768 * 2));
  (void)ws_size; (void)in_sizes; (void)n_in; (void)out_size;

  // weight bf16 transposes (per replay; ~510MB traffic, amortized small)
  wt_transpose<<<dim3(2304 / 32, 768 / 32, 12), 256, 0, stream>>>(caw, wt_attn, 768, 2304);
  wt_transpose<<<dim3(768 / 32, 768 / 32, 12), 256, 0, stream>>>(apw, wt_proj, 768, 768);
  wt_transpose<<<dim3(3072 / 32, 768 / 32, 12), 256, 0, stream>>>(fw, wt_fc, 768, 3072);
  wt_transpose<<<dim3(768 / 32, 3072 / 32, 12), 256, 0, stream>>>(pw, wt_mlp, 3072, 768);

  embed_k<<<8192, 256, 0, stream>>>(x, pos, h, hbf);

  for (int L = 0; L < 12; ++L) {
    gemm_bt<128, 1><<<dim3(64, 18), 256, 0, stream>>>(
        hbf, wt_attn + (size_t)L * 2304 * 768, cab + (size_t)L * 2304, qkvb, 2304, 768);
    attn_k<<<dim3(8, 12, 16), 256, 0, stream>>>(qkvb, mask, obf);
    gemm_bt<64, 0><<<dim3(64, 12), 256, 0, stream>>>(
        obf, wt_proj + (size_t)L * 768 * 768, apb + (size_t)L * 768, aout, 768, 768);
    ln_fused<<<8192, 256, 0, stream>>>(h, aout, g1 + (size_t)L * 768,
                                       b1 + (size_t)L * 768, nrm, nbf);
    gemm_bt<128, 2><<<dim3(64, 24), 256, 0, stream>>>(
        nbf, wt_fc + (size_t)L * 768 * 3072, fb + (size_t)L * 3072, gbf, 3072, 768);
    gemm_bt<64, 0><<<dim3(64, 12), 256, 0, stream>>>(
        gbf, wt_mlp + (size_t)L * 3072 * 768, pb + (size_t)L * 768, aout, 768, 3072);
    ln_fused<<<8192, 256, 0, stream>>>(nrm, aout, g2 + (size_t)L * 768,
                                       b2 + (size_t)L * 768, h, hbf);
  }

  final_k<<<8192, 256, 0, stream>>>(h, (float*)d_out);
}